// Round 1
// baseline (908.221 us; speedup 1.0000x reference)
//
#include <hip/hip_runtime.h>
#include <math.h>

#define LBL   8
#define DIM   96
#define PLANE (DIM*DIM)          // 9216
#define NVOX  (DIM*DIM*DIM)      // 884736
#define GD0 14
#define GD1 14
#define GD2 14
#define GD3 10
#define GSIZE (GD0*GD1*GD2*GD3)  // 27440
#define ST0 1960
#define ST1 140
#define ST2 10
#define CH  12                   // padded channel stride (9 used)
#define GRIDF (GSIZE*CH)         // 329280 floats

// normalized Gaussian weights, sigma=3, radius=9 (by |t|)
__constant__ float GW[10] = {
    0.13317604f, 0.12597912f, 0.10663904f, 0.08077540f, 0.05475300f,
    0.03320771f, 0.01802341f, 0.00875346f, 0.00380423f, 0.00147945f
};

// ---------------------------------------------------------------------------
// Kernel A: per-voxel softmax over labels + 4-D bilateral-grid splat.
// Block = 32x8x8 voxels (512 threads, thread covers 4 z-slices).
// All voxels of the block share lattice cells (bz,by,bx*4..bx*4+3) exactly.
// LDS: 4 privatized copies of the 2x2x5x10 x 9ch footprint (1800 floats).
// ---------------------------------------------------------------------------
__global__ __launch_bounds__(512)
void k_softmax_splat(const float* __restrict__ U, const float* __restrict__ img,
                     float* __restrict__ q, float* __restrict__ grid)
{
    __shared__ float sg[4][1800];
    const int tid = threadIdx.x;
    for (int i = tid; i < 4*1800; i += 512) ((float*)sg)[i] = 0.f;
    __syncthreads();

    const int bid = blockIdx.x;
    const int bx = bid % 3;
    const int by = (bid / 3) % 12;
    const int bz = bid / 36;
    const int x0 = bx * 32, y0 = by * 8, z0 = bz * 8;

    const int lx  = tid & 31;
    const int ly  = (tid >> 5) & 7;
    const int lzb = tid >> 8;          // 0..1
    float* sgc = sg[(tid >> 7) & 3];   // 2 waves per copy

    const int x = x0 + lx;
    const int y = y0 + ly;
    const float fx = (float)(lx & 7) * 0.125f;
    const float fy = (float)ly * 0.125f;
    const int cellx = lx >> 3;         // 0..3

    for (int s = 0; s < 4; ++s) {
        const int z = z0 + lzb + 2 * s;
        const int vox = z * PLANE + y * DIM + x;

        float u[LBL];
        float m = -1e30f;
        #pragma unroll
        for (int l = 0; l < LBL; ++l) { u[l] = U[l*NVOX + vox]; m = fmaxf(m, u[l]); }
        float ssum = 0.f;
        #pragma unroll
        for (int l = 0; l < LBL; ++l) { u[l] = expf(u[l] - m); ssum += u[l]; }
        const float inv = 1.f / ssum;
        #pragma unroll
        for (int l = 0; l < LBL; ++l) { u[l] *= inv; q[l*NVOX + vox] = u[l]; }

        const float f = img[vox] * 8.0f;     // img / BETA (exact)
        int li = (int)floorf(f);
        li = li < 0 ? 0 : (li > 8 ? 8 : li);
        const float fi = f - (float)li;
        const float fz = (float)(z & 7) * 0.125f;
        const float wz[2] = {1.f - fz, fz};
        const float wy[2] = {1.f - fy, fy};
        const float wx[2] = {1.f - fx, fx};
        const float wi[2] = {1.f - fi, fi};

        #pragma unroll
        for (int i2 = 0; i2 < 2; ++i2)
        #pragma unroll
        for (int j2 = 0; j2 < 2; ++j2)
        #pragma unroll
        for (int k2 = 0; k2 < 2; ++k2) {
            const float wsp = wz[i2] * wy[j2] * wx[k2];
            if (wsp == 0.f) continue;
            const int cb = (((i2*2 + j2)*5) + cellx + k2) * 10 + li;
            #pragma unroll
            for (int m2 = 0; m2 < 2; ++m2) {
                const float w = wsp * wi[m2];
                if (w == 0.f) continue;
                float* p = &sgc[(cb + m2) * 9];
                #pragma unroll
                for (int c = 0; c < LBL; ++c) atomicAdd(&p[c], w * u[c]);
                atomicAdd(&p[LBL], w);
            }
        }
    }
    __syncthreads();

    for (int idx = tid; idx < 1800; idx += 512) {
        const float v = sg[0][idx] + sg[1][idx] + sg[2][idx] + sg[3][idx];
        if (v != 0.f) {
            const int c = idx % 9;
            int rest = idx / 9;
            const int g  = rest % 10; rest /= 10;
            const int xc = rest % 5;  rest /= 5;
            const int j2 = rest & 1;
            const int i2 = rest >> 1;
            const int cell = (bz + i2)*ST0 + (by + j2)*ST1 + (bx*4 + xc)*ST2 + g;
            atomicAdd(&grid[cell*CH + c], v);
        }
    }
}

// ---------------------------------------------------------------------------
// Separable 19-tap Gaussian along axis AX (0=z,1=y,2=x), zero-padded.
// ---------------------------------------------------------------------------
template<int AX>
__global__ __launch_bounds__(256)
void k_gauss(const float* __restrict__ src, float* __restrict__ dst)
{
    const int id = blockIdx.x * 256 + threadIdx.x;
    if (id >= LBL * NVOX) return;
    const int rem = id % NVOX;
    int c, stride;
    if (AX == 0)      { c = rem / PLANE;        stride = PLANE; }
    else if (AX == 1) { c = (rem / DIM) % DIM;  stride = DIM; }
    else              { c = rem % DIM;          stride = 1; }
    float acc = 0.f;
    #pragma unroll
    for (int t = -9; t <= 9; ++t) {
        const int cc = c + t;
        if (cc >= 0 && cc < DIM) acc += GW[t < 0 ? -t : t] * src[id + t*stride];
    }
    dst[id] = acc;
}

// ---------------------------------------------------------------------------
// [1,2,1]/4 blur along grid axis AX (0..3), zero-padded. Operates on CH=12
// padded channels (padding stays zero).
// ---------------------------------------------------------------------------
template<int AX>
__global__ __launch_bounds__(256)
void k_blur(const float* __restrict__ src, float* __restrict__ dst)
{
    const int id = blockIdx.x * 256 + threadIdx.x;
    if (id >= GRIDF) return;
    const int cell = id / CH;
    int c, ext, stride;
    if (AX == 0)      { c = cell / ST0;         ext = GD0; stride = ST0; }
    else if (AX == 1) { c = (cell / ST1) % GD1; ext = GD1; stride = ST1; }
    else if (AX == 2) { c = (cell / ST2) % GD2; ext = GD2; stride = ST2; }
    else              { c = cell % GD3;         ext = GD3; stride = 1; }
    const float mid = src[id];
    const float a = (c > 0)       ? src[id - stride*CH] : 0.f;
    const float b = (c < ext - 1) ? src[id + stride*CH] : 0.f;
    dst[id] = 0.25f*a + 0.5f*mid + 0.25f*b;
}

// ---------------------------------------------------------------------------
// CS = C@S, CB = C@B  (8x8 each) -> mats[0..63], mats[64..127]
// ---------------------------------------------------------------------------
__global__ void k_matprep(const float* __restrict__ Cm, const float* __restrict__ Sm,
                          const float* __restrict__ Bm, float* __restrict__ mats)
{
    const int t = threadIdx.x;
    if (t < 64) {
        const int i = t >> 3, j = t & 7;
        float cs = 0.f, cb = 0.f;
        for (int k = 0; k < 8; ++k) {
            cs += Cm[i*8 + k] * Sm[k*8 + j];
            cb += Cm[i*8 + k] * Bm[k*8 + j];
        }
        mats[t] = cs;
        mats[64 + t] = cb;
    }
}

// ---------------------------------------------------------------------------
// Final: slice bilateral grid, normalize, Qp = CS@sp + CB@bi,
// out = softmax(U + Qp). Reads sp from d_out (own indices) then overwrites.
// ---------------------------------------------------------------------------
__global__ __launch_bounds__(256)
void k_final(const float* __restrict__ U, const float* __restrict__ img,
             const float* sp, const float* __restrict__ grid,
             const float* __restrict__ mats, float* out)
{
    __shared__ float sm[128];
    if (threadIdx.x < 128) sm[threadIdx.x] = mats[threadIdx.x];
    __syncthreads();

    const int vox = blockIdx.x * 256 + threadIdx.x;
    if (vox >= NVOX) return;
    const int z = vox / PLANE;
    const int y = (vox / DIM) % DIM;
    const int x = vox % DIM;
    const int lz = z >> 3, lyc = y >> 3, lxc = x >> 3;
    const float fz = (float)(z & 7) * 0.125f;
    const float fy = (float)(y & 7) * 0.125f;
    const float fx = (float)(x & 7) * 0.125f;
    const float f = img[vox] * 8.0f;
    int li = (int)floorf(f);
    li = li < 0 ? 0 : (li > 8 ? 8 : li);
    const float fi = f - (float)li;
    const float wz[2]  = {1.f - fz, fz};
    const float wyv[2] = {1.f - fy, fy};
    const float wxv[2] = {1.f - fx, fx};
    const float wiv[2] = {1.f - fi, fi};

    float acc[9];
    #pragma unroll
    for (int c = 0; c < 9; ++c) acc[c] = 0.f;

    #pragma unroll
    for (int i2 = 0; i2 < 2; ++i2)
    #pragma unroll
    for (int j2 = 0; j2 < 2; ++j2)
    #pragma unroll
    for (int k2 = 0; k2 < 2; ++k2) {
        const float wsp = wz[i2] * wyv[j2] * wxv[k2];
        const int cellbase = (lz+i2)*ST0 + (lyc+j2)*ST1 + (lxc+k2)*ST2 + li;
        #pragma unroll
        for (int m2 = 0; m2 < 2; ++m2) {
            const float w = wsp * wiv[m2];
            const float* p = &grid[(cellbase + m2) * CH];
            const float4 p0 = *reinterpret_cast<const float4*>(p);
            const float4 p1 = *reinterpret_cast<const float4*>(p + 4);
            acc[0] += w * p0.x; acc[1] += w * p0.y; acc[2] += w * p0.z; acc[3] += w * p0.w;
            acc[4] += w * p1.x; acc[5] += w * p1.y; acc[6] += w * p1.z; acc[7] += w * p1.w;
            acc[8] += w * p[8];
        }
    }
    const float dinv = 1.f / (acc[8] + 1e-8f);
    float bi[8], spv[8], u[8];
    #pragma unroll
    for (int l = 0; l < 8; ++l) {
        bi[l]  = acc[l] * dinv;
        spv[l] = sp[l*NVOX + vox];
        u[l]   = U[l*NVOX + vox];
    }
    float v[8];
    float mx = -1e30f;
    #pragma unroll
    for (int i = 0; i < 8; ++i) {
        float t = 0.f;
        #pragma unroll
        for (int l = 0; l < 8; ++l) t += sm[i*8 + l] * spv[l] + sm[64 + i*8 + l] * bi[l];
        v[i] = u[i] + t;
        mx = fmaxf(mx, v[i]);
    }
    float ssum = 0.f;
    #pragma unroll
    for (int i = 0; i < 8; ++i) { v[i] = expf(v[i] - mx); ssum += v[i]; }
    const float inv = 1.f / ssum;
    #pragma unroll
    for (int i = 0; i < 8; ++i) out[i*NVOX + vox] = v[i] * inv;
}

extern "C" void kernel_launch(void* const* d_in, const int* in_sizes, int n_in,
                              void* d_out, int out_size, void* d_ws, size_t ws_size,
                              hipStream_t stream)
{
    const float* U   = (const float*)d_in[0];
    const float* img = (const float*)d_in[1];
    const float* Sw  = (const float*)d_in[2];
    const float* Bw  = (const float*)d_in[3];
    const float* Cm  = (const float*)d_in[4];
    float* out = (float*)d_out;
    float* ws  = (float*)d_ws;

    float* q     = ws;                          // 7077888 floats
    float* gridA = ws + (size_t)LBL * NVOX;     // 329280 floats
    float* gridB = gridA + GRIDF;               // 329280 floats
    float* mats  = gridB + GRIDF;               // 128 floats

    hipMemsetAsync(gridA, 0, GRIDF * sizeof(float), stream);
    k_matprep<<<1, 64, 0, stream>>>(Cm, Sw, Bw, mats);

    k_softmax_splat<<<432, 512, 0, stream>>>(U, img, q, gridA);

    const int gth = LBL * NVOX;
    k_gauss<2><<<(gth + 255)/256, 256, 0, stream>>>(q,   out);  // x
    k_gauss<1><<<(gth + 255)/256, 256, 0, stream>>>(out, q);    // y
    k_gauss<0><<<(gth + 255)/256, 256, 0, stream>>>(q,   out);  // z -> sp in out

    k_blur<0><<<(GRIDF + 255)/256, 256, 0, stream>>>(gridA, gridB);
    k_blur<1><<<(GRIDF + 255)/256, 256, 0, stream>>>(gridB, gridA);
    k_blur<2><<<(GRIDF + 255)/256, 256, 0, stream>>>(gridA, gridB);
    k_blur<3><<<(GRIDF + 255)/256, 256, 0, stream>>>(gridB, gridA);

    k_final<<<(NVOX + 255)/256, 256, 0, stream>>>(U, img, out, gridA, mats, out);
}